// Round 17
// baseline (113.920 us; speedup 1.0000x reference)
//
#include <hip/hip_runtime.h>

// IGANN: per-feature 2-layer MLPs (1->16->16->1), summed over 256 features + linear term.
// R17: R15's hypothesis (barrier-free x breaks the stage/compute phase lock-step that
//     pins R9/R10/R14 at ~32 us regardless of blocks/CU) rebuilt as a MINIMAL delta on
//     the R14 skeleton, since R15/R16 containers died twice while R14 ran:
//     - NO f16x8 LDS stores, NO __builtin_shufflevector, NO packed W1|b1 (R15's novel
//       constructs — prime suspects for the container kills). Staging is R14-verbatim.
//     - x read directly from global into VGPRs (f32x4/tile, one-chunk-ahead prefetch) —
//       same access pattern class as R4 which ran. x is wave-private: no LDS, no barrier.
//     - lin computed in-loop from the f32 x values; g==0 lanes deliver it via atomicAdd.
//     - LDS 11264 B (w2s 8192 f16 + w1s/b1s 1024 f16 + b2s/w3s 2048 f32).
//     - plain __launch_bounds__(256): min-waves>=4 spilled 100s of MB (R3/R4/R8).

typedef float    f32x4 __attribute__((ext_vector_type(4)));
typedef _Float16 f16x4 __attribute__((ext_vector_type(4)));
typedef __fp16   pk16x2 __attribute__((ext_vector_type(2)));

__device__ __forceinline__ f16x4 cvt4(f32x4 v) {
    pk16x2 lo = __builtin_amdgcn_cvt_pkrtz(v[0], v[1]);
    pk16x2 hi = __builtin_amdgcn_cvt_pkrtz(v[2], v[3]);
    union { unsigned u[2]; f16x4 h; } un;
    un.u[0] = __builtin_bit_cast(unsigned, lo);
    un.u[1] = __builtin_bit_cast(unsigned, hi);
    return un.h;
}

__device__ __forceinline__ f16x4 relu_h(f16x4 v) {
    f16x4 z = {};
    return __builtin_elementwise_max(v, z);
}

__device__ __forceinline__ f32x4 relu_f(f32x4 v) {
    f32x4 z = {0.f, 0.f, 0.f, 0.f};
    return __builtin_elementwise_max(v, z);
}

#define FCHUNK 16   // features per block (16 groups of 16 = 256)

__global__ __launch_bounds__(256) void igann_kernel(
    const float* __restrict__ x,  const float* __restrict__ la,
    const float* __restrict__ bb, const float* __restrict__ W1,
    const float* __restrict__ b1, const float* __restrict__ W2,
    const float* __restrict__ b2, const float* __restrict__ W3,
    const float* __restrict__ b3, float* __restrict__ out)
{
    const int tid = threadIdx.x;
    const int l   = tid & 63;     // lane
    const int w   = tid >> 6;     // wave in block (0..3)
    const int r   = l & 15;       // MFMA row m (A) / col n (D)
    const int g   = l >> 4;       // k-group
    const int g4  = g * 4;

    const int rb = blockIdx.x >> 4;    // row block (0..127), 256 rows each
    const int fg = blockIdx.x & 15;    // feature group (0..15)
    const int f0 = fg * FCHUNK;
    const int rowbase = rb * 256;

    __shared__ _Float16 w2s[FCHUNK * 16 * 16];   // 8192 B: [f][n][k16] dense
    __shared__ _Float16 w1s[FCHUNK * 16];        //  512 B: [f][k]
    __shared__ _Float16 b1s[FCHUNK * 16];        //  512 B
    __shared__ float    b2s[FCHUNK * 16];        // 1024 B: [f][n]
    __shared__ float    w3s[FCHUNK * 16];        // 1024 B   -> 11264 B total

    // ---- stage W2 (thread tid owns (f,n)=(tid>>4, tid&15)) — R14-verbatim ----
    {
        const int f = tid >> 4, n = tid & 15;
        const float* src = W2 + ((size_t)(f0 + f) * 16 + n) * 16;
        _Float16* dst = w2s + (f * 16 + n) * 16;
        #pragma unroll
        for (int q = 0; q < 4; ++q) {
            f32x4 v = *(const f32x4*)(src + q * 4);
            *(f16x4*)(dst + q * 4) = cvt4(v);
        }
    }
    // ---- stage W1/b1 (f16), b2/W3 (f32): one element per thread — R14-verbatim ----
    w1s[tid] = (_Float16)W1[f0 * 16 + tid];
    b1s[tid] = (_Float16)b1[f0 * 16 + tid];
    b2s[tid] = b2[f0 * 16 + tid];
    w3s[tid] = W3[f0 * 16 + tid];
    __syncthreads();
    // -------- no barriers from here on: waves free-run --------

    // uniform constants (SALU)
    float b3s = 0.f;
    #pragma unroll
    for (int c = 0; c < FCHUNK; ++c) b3s += b3[f0 + c];
    const float gconst = b3s + (fg == 0 ? bb[0] : 0.f);

    // lane's x pointer: row = rowbase + w*64 + t*16 + r (wave-private rows)
    const float* xbase = x + (size_t)(rowbase + w * 64 + r) * 256 + f0;

    f32x4 acc[4];     // [tile][j]: D row g4+j, col r (channel)
    float lin[4];
    #pragma unroll
    for (int t = 0; t < 4; ++t) { acc[t] = (f32x4){0.f, 0.f, 0.f, 0.f}; lin[t] = 0.f; }

    f32x4 xf[4], xn[4];
    #pragma unroll
    for (int t = 0; t < 4; ++t)
        xf[t] = *(const f32x4*)(xbase + t * 16 * 256);

    for (int fi = 0; fi < FCHUNK; fi += 4) {   // rolled: keeps register pressure down
        if (fi < FCHUNK - 4) {
            #pragma unroll
            for (int t = 0; t < 4; ++t)
                xn[t] = *(const f32x4*)(xbase + t * 16 * 256 + fi + 4);
        }
        f16x4 xh[4];
        #pragma unroll
        for (int t = 0; t < 4; ++t) xh[t] = cvt4(xf[t]);

        // linear term from the f32 values (la is wave-uniform -> s_loads)
        #pragma unroll
        for (int t = 0; t < 4; ++t)
            #pragma unroll
            for (int c = 0; c < 4; ++c)
                lin[t] = fmaf(xf[t][c], la[f0 + fi + c], lin[t]);

        #pragma unroll
        for (int u = 0; u < 4; ++u) {
            const int f = fi + u;
            f16x4 w1h   = *(const f16x4*)(w1s + f * 16 + g4);
            f16x4 b1h   = *(const f16x4*)(b1s + f * 16 + g4);
            f16x4 bfrag = *(const f16x4*)(w2s + (f * 16 + r) * 16 + g4);
            const float b2k = b2s[f * 16 + r];
            const float w3k = w3s[f * 16 + r];
            const f32x4 cinit = {b2k, b2k, b2k, b2k};   // b2 folded into MFMA C
            const f32x4 w3k4  = {w3k, w3k, w3k, w3k};

            #pragma unroll
            for (int t = 0; t < 4; ++t) {
                const _Float16 s = xh[t][u];
                f16x4 xb = {s, s, s, s};
                f16x4 h = relu_h(xb * w1h + b1h);       // v_pk_fma_f16 + v_pk_max_f16
                f32x4 d = __builtin_amdgcn_mfma_f32_16x16x16f16(h, bfrag, cinit, 0, 0, 0);
                acc[t] += relu_f(d) * w3k4;
            }
        }
        if (fi < FCHUNK - 4) {
            #pragma unroll
            for (int t = 0; t < 4; ++t) xf[t] = xn[t];
        }
    }

    // ---- channel reduce (lane bits 0..3); r==0 lanes atomic the subnet sums ----
    #pragma unroll
    for (int t = 0; t < 4; ++t)
        #pragma unroll
        for (int j = 0; j < 4; ++j) {
            float v = acc[t][j];
            v += __shfl_xor(v, 1, 64);
            v += __shfl_xor(v, 2, 64);
            v += __shfl_xor(v, 4, 64);
            v += __shfl_xor(v, 8, 64);
            if (r == 0)
                atomicAdd(out + rowbase + w * 64 + t * 16 + g4 + j, v);
        }

    // ---- linear term + constants: g==0 lanes own rows t*16+r ----
    if (g == 0) {
        #pragma unroll
        for (int t = 0; t < 4; ++t)
            atomicAdd(out + rowbase + w * 64 + t * 16 + r, lin[t] + gconst);
    }
}

extern "C" void kernel_launch(void* const* d_in, const int* in_sizes, int n_in,
                              void* d_out, int out_size, void* d_ws, size_t ws_size,
                              hipStream_t stream) {
    const float* x  = (const float*)d_in[0];
    const float* la = (const float*)d_in[1];
    const float* bb = (const float*)d_in[2];
    const float* W1 = (const float*)d_in[3];
    const float* b1 = (const float*)d_in[4];
    const float* W2 = (const float*)d_in[5];
    const float* b2 = (const float*)d_in[6];
    const float* W3 = (const float*)d_in[7];
    const float* b3 = (const float*)d_in[8];
    float* out = (float*)d_out;

    (void)hipMemsetAsync(out, 0, (size_t)out_size * sizeof(float), stream);

    dim3 grid(2048), block(256);   // 128 row-blocks x 16 feature-groups
    hipLaunchKernelGGL(igann_kernel, grid, block, 0, stream,
                       x, la, bb, W1, b1, W2, b2, W3, b3, out);
}

// Round 18
// 110.895 us; speedup vs baseline: 1.0273x; 1.0273x over previous
//
#include <hip/hip_runtime.h>

// IGANN: per-feature 2-layer MLPs (1->16->16->1), summed over 256 features + linear term.
// R18: test the LAST unvaried structural element — the 1M device-scope atomicAdds into the
//     128-KB out buffer (16 groups x 2 RMW/row, cross-XCD line contention) + out memset.
//     R9/R14/R17 pinned at ~32-37 us across all staging/barrier/residency variants while
//     the compute floor is ~6 us -> atomics are the prime remaining suspect.
//     kernel1 = R14 skeleton (LDS-resident f16 weights + f16 x staging, stable constructs
//     only), but partials go to d_ws with plain coalesced stores:
//       ws1[fg][row] = subnet sum, ws2[fg][row] = lin + b3s (per-group).
//     kernel2 (128 blocks): out[row] = bb + sum_fg(ws1+ws2) — single plain store, no memset.

typedef float    f32x4 __attribute__((ext_vector_type(4)));
typedef _Float16 f16x4 __attribute__((ext_vector_type(4)));
typedef __fp16   pk16x2 __attribute__((ext_vector_type(2)));

__device__ __forceinline__ f16x4 cvt4(f32x4 v) {
    pk16x2 lo = __builtin_amdgcn_cvt_pkrtz(v[0], v[1]);
    pk16x2 hi = __builtin_amdgcn_cvt_pkrtz(v[2], v[3]);
    union { unsigned u[2]; f16x4 h; } un;
    un.u[0] = __builtin_bit_cast(unsigned, lo);
    un.u[1] = __builtin_bit_cast(unsigned, hi);
    return un.h;
}

__device__ __forceinline__ f16x4 relu_h(f16x4 v) {
    f16x4 z = {};
    return __builtin_elementwise_max(v, z);
}

__device__ __forceinline__ f32x4 relu_f(f32x4 v) {
    f32x4 z = {0.f, 0.f, 0.f, 0.f};
    return __builtin_elementwise_max(v, z);
}

#define FCHUNK 16   // features per block (16 groups of 16 = 256)
#define NROWS  32768
#define XR     20   // x LDS row stride in f16 (40 B, 8-B aligned, conflict-free — R9-proven)

__global__ __launch_bounds__(256) void igann_part1(
    const float* __restrict__ x,  const float* __restrict__ la,
    const float* __restrict__ W1, const float* __restrict__ b1,
    const float* __restrict__ W2, const float* __restrict__ b2,
    const float* __restrict__ W3, const float* __restrict__ b3,
    float* __restrict__ ws1, float* __restrict__ ws2)
{
    const int tid = threadIdx.x;
    const int l   = tid & 63;     // lane
    const int w   = tid >> 6;     // wave in block (0..3)
    const int r   = l & 15;       // MFMA row m (A) / col n (D)
    const int g   = l >> 4;       // k-group
    const int g4  = g * 4;

    const int rb = blockIdx.x >> 4;    // row block (0..127), 256 rows each
    const int fg = blockIdx.x & 15;    // feature group (0..15)
    const int f0 = fg * FCHUNK;
    const int rowbase = rb * 256;

    __shared__ _Float16 xs [256 * XR];           // 10240 B: x slice [row][col16+pad]
    __shared__ _Float16 w2s[FCHUNK * 16 * 16];   //  8192 B: [f][n][k16] dense
    __shared__ _Float16 w1s[FCHUNK * 16];        //   512 B: [f][k]
    __shared__ _Float16 b1s[FCHUNK * 16];        //   512 B
    __shared__ float    b2s[FCHUNK * 16];        //  1024 B: [f][n]
    __shared__ float    w3s[FCHUNK * 16];        //  1024 B  -> 21504 B total

    // ---- stage x slice (coalesced: 4 lanes cover one 64-B row-slice) ----
    {
        const int rr = tid >> 2;          // 0..63
        const int c4 = (tid & 3) * 4;     // 0,4,8,12
        #pragma unroll
        for (int it = 0; it < 4; ++it) {
            const int row = it * 64 + rr;
            f32x4 v = *(const f32x4*)(x + (size_t)(rowbase + row) * 256 + f0 + c4);
            *(f16x4*)(xs + row * XR + c4) = cvt4(v);
        }
    }
    // ---- stage W2 (thread tid owns (f,n)=(tid>>4, tid&15)) ----
    {
        const int f = tid >> 4, n = tid & 15;
        const float* src = W2 + ((size_t)(f0 + f) * 16 + n) * 16;
        _Float16* dst = w2s + (f * 16 + n) * 16;
        #pragma unroll
        for (int q = 0; q < 4; ++q) {
            f32x4 v = *(const f32x4*)(src + q * 4);
            *(f16x4*)(dst + q * 4) = cvt4(v);
        }
    }
    // ---- stage W1/b1 (f16), b2/W3 (f32): one element per thread ----
    w1s[tid] = (_Float16)W1[f0 * 16 + tid];
    b1s[tid] = (_Float16)b1[f0 * 16 + tid];
    b2s[tid] = b2[f0 * 16 + tid];
    w3s[tid] = W3[f0 * 16 + tid];
    __syncthreads();

    const _Float16* xw = xs + (w * 64 + r) * XR;

    f32x4 acc[4];     // [tile][j]: D row g4+j (batch row within tile), col r (channel)
    #pragma unroll
    for (int t = 0; t < 4; ++t) acc[t] = (f32x4){0.f, 0.f, 0.f, 0.f};

    for (int fi = 0; fi < FCHUNK; fi += 4) {   // rolled: keeps register pressure down
        f16x4 xv[4];
        #pragma unroll
        for (int t = 0; t < 4; ++t)
            xv[t] = *(const f16x4*)(xw + t * 16 * XR + fi);

        #pragma unroll
        for (int u = 0; u < 4; ++u) {
            const int f = fi + u;
            f16x4 w1h   = *(const f16x4*)(w1s + f * 16 + g4);
            f16x4 b1h   = *(const f16x4*)(b1s + f * 16 + g4);
            f16x4 bfrag = *(const f16x4*)(w2s + (f * 16 + r) * 16 + g4);
            const float b2k = b2s[f * 16 + r];
            const float w3k = w3s[f * 16 + r];
            const f32x4 cinit = {b2k, b2k, b2k, b2k};   // b2 folded into MFMA C
            const f32x4 w3k4  = {w3k, w3k, w3k, w3k};

            #pragma unroll
            for (int t = 0; t < 4; ++t) {
                const _Float16 s = xv[t][u];
                f16x4 xb = {s, s, s, s};
                f16x4 h = relu_h(xb * w1h + b1h);       // v_pk_fma_f16 + v_pk_max_f16
                f32x4 d = __builtin_amdgcn_mfma_f32_16x16x16f16(h, bfrag, cinit, 0, 0, 0);
                acc[t] += relu_f(d) * w3k4;
            }
        }
    }

    // ---- channel reduce (lane bits 0..3); r==0 lanes store per-row subnet sums ----
    float* w1out = ws1 + (size_t)fg * NROWS + rowbase;
    #pragma unroll
    for (int t = 0; t < 4; ++t)
        #pragma unroll
        for (int j = 0; j < 4; ++j) {
            float v = acc[t][j];
            v += __shfl_xor(v, 1, 64);
            v += __shfl_xor(v, 2, 64);
            v += __shfl_xor(v, 4, 64);
            v += __shfl_xor(v, 8, 64);
            if (r == 0)
                w1out[w * 64 + t * 16 + g4 + j] = v;    // plain store, no contention
        }

    // ---- linear term + b3: g==0 lanes own rows t*16+r (xs intact, read-only) ----
    float b3s = 0.f;
    #pragma unroll
    for (int c = 0; c < FCHUNK; ++c) b3s += b3[f0 + c];   // uniform -> s_loads
    if (g == 0) {
        float* w2out = ws2 + (size_t)fg * NROWS + rowbase;
        #pragma unroll
        for (int t = 0; t < 4; ++t) {
            const int row = w * 64 + t * 16 + r;
            float lin = 0.f;
            const _Float16* xrow = xs + row * XR;
            #pragma unroll
            for (int c = 0; c < FCHUNK; ++c)
                lin = fmaf((float)xrow[c], la[f0 + c], lin);
            w2out[row] = lin + b3s;                     // plain store
        }
    }
}

__global__ __launch_bounds__(256) void igann_part2(
    const float* __restrict__ ws1, const float* __restrict__ ws2,
    const float* __restrict__ bb,  float* __restrict__ out)
{
    const int row = blockIdx.x * 256 + threadIdx.x;
    float s = bb[0];
    #pragma unroll
    for (int fgi = 0; fgi < 16; ++fgi)
        s += ws1[(size_t)fgi * NROWS + row] + ws2[(size_t)fgi * NROWS + row];
    out[row] = s;
}

extern "C" void kernel_launch(void* const* d_in, const int* in_sizes, int n_in,
                              void* d_out, int out_size, void* d_ws, size_t ws_size,
                              hipStream_t stream) {
    const float* x  = (const float*)d_in[0];
    const float* la = (const float*)d_in[1];
    const float* bb = (const float*)d_in[2];
    const float* W1 = (const float*)d_in[3];
    const float* b1 = (const float*)d_in[4];
    const float* W2 = (const float*)d_in[5];
    const float* b2 = (const float*)d_in[6];
    const float* W3 = (const float*)d_in[7];
    const float* b3 = (const float*)d_in[8];
    float* out = (float*)d_out;

    float* ws1 = (float*)d_ws;                    // 16 x 32768 f32 = 2 MB
    float* ws2 = ws1 + (size_t)16 * NROWS;        // 16 x 32768 f32 = 2 MB

    dim3 grid1(2048), block(256);   // 128 row-blocks x 16 feature-groups
    hipLaunchKernelGGL(igann_part1, grid1, block, 0, stream,
                       x, la, W1, b1, W2, b2, W3, b3, ws1, ws2);

    dim3 grid2(NROWS / 256);
    hipLaunchKernelGGL(igann_part2, grid2, block, 0, stream,
                       ws1, ws2, bb, out);
}

// Round 19
// 107.833 us; speedup vs baseline: 1.0564x; 1.0284x over previous
//
#include <hip/hip_runtime.h>

// IGANN: per-feature 2-layer MLPs (1->16->16->1), summed over 256 features + linear term.
// R19 = R14 single-kernel base (best stable 109.1; atomics exonerated by R18's ws-store
//     variant at 110.9) + LDS-op diet. Structural axes (residency 4/6/8 blk/CU, barriers
//     2/1/0, atomics vs stores) are all FLAT at kernel ~32-37 us -> attack issue count:
//     - W1|b1 interleaved [f][g][w1x4|b1x4]: the two in-loop f16x4 reads are adjacent
//       (8 B apart) -> ds_read2_b64 merge. Staged with scalar f16 stores (proven class;
//       NO f16x8 stores / shufflevector — those correlate with the R15/R16 container kills).
//     - (b2,w3) as interleaved float2 -> one ds_read_b64 instead of two b32.
//     Per-u LDS ops 5 -> 3 (~32 fewer ds_read/wave + addressing).
//     LDS 11264 B total. Plain launch_bounds(256) (min-waves>=4 spills — R3/R4/R8).

typedef float    f32x4 __attribute__((ext_vector_type(4)));
typedef _Float16 f16x4 __attribute__((ext_vector_type(4)));
typedef __fp16   pk16x2 __attribute__((ext_vector_type(2)));

__device__ __forceinline__ f16x4 cvt4(f32x4 v) {
    pk16x2 lo = __builtin_amdgcn_cvt_pkrtz(v[0], v[1]);
    pk16x2 hi = __builtin_amdgcn_cvt_pkrtz(v[2], v[3]);
    union { unsigned u[2]; f16x4 h; } un;
    un.u[0] = __builtin_bit_cast(unsigned, lo);
    un.u[1] = __builtin_bit_cast(unsigned, hi);
    return un.h;
}

__device__ __forceinline__ f16x4 relu_h(f16x4 v) {
    f16x4 z = {};
    return __builtin_elementwise_max(v, z);
}

__device__ __forceinline__ f32x4 relu_f(f32x4 v) {
    f32x4 z = {0.f, 0.f, 0.f, 0.f};
    return __builtin_elementwise_max(v, z);
}

#define FCHUNK 16   // features per block (16 groups of 16 = 256)
#define XR     20   // x LDS row stride in f16 (40 B, 8-B aligned, conflict-free — R9-proven)

__global__ __launch_bounds__(256) void igann_kernel(
    const float* __restrict__ x,  const float* __restrict__ la,
    const float* __restrict__ bb, const float* __restrict__ W1,
    const float* __restrict__ b1, const float* __restrict__ W2,
    const float* __restrict__ b2, const float* __restrict__ W3,
    const float* __restrict__ b3, float* __restrict__ out)
{
    const int tid = threadIdx.x;
    const int l   = tid & 63;     // lane
    const int w   = tid >> 6;     // wave in block (0..3)
    const int r   = l & 15;       // MFMA row m (A) / col n (D)
    const int g   = l >> 4;       // k-group
    const int g4  = g * 4;

    const int rb = blockIdx.x >> 4;    // row block (0..127), 256 rows each
    const int fg = blockIdx.x & 15;    // feature group (0..15)
    const int f0 = fg * FCHUNK;
    const int rowbase = rb * 256;

    __shared__ _Float16 xs [256 * XR];           // 10240 B: x slice [row][col16+pad]
    __shared__ _Float16 w2s[FCHUNK * 16 * 16];   //  8192 B: [f][n][k16] dense
    __shared__ _Float16 wbs[FCHUNK * 4 * 8];     //  1024 B: [f][g][w1 x4 | b1 x4]
    __shared__ float2   bws[FCHUNK * 16];        //  2048 B: [f][n] -> (b2, w3)
                                                 //  -> 21504 B total

    // ---- stage x slice (coalesced: 4 lanes cover one 64-B row-slice) ----
    {
        const int rr = tid >> 2;          // 0..63
        const int c4 = (tid & 3) * 4;     // 0,4,8,12
        #pragma unroll
        for (int it = 0; it < 4; ++it) {
            const int row = it * 64 + rr;
            f32x4 v = *(const f32x4*)(x + (size_t)(rowbase + row) * 256 + f0 + c4);
            *(f16x4*)(xs + row * XR + c4) = cvt4(v);
        }
    }
    // ---- stage W2 (thread tid owns (f,n)=(tid>>4, tid&15)) — R14-verbatim ----
    {
        const int f = tid >> 4, n = tid & 15;
        const float* src = W2 + ((size_t)(f0 + f) * 16 + n) * 16;
        _Float16* dst = w2s + (f * 16 + n) * 16;
        #pragma unroll
        for (int q = 0; q < 4; ++q) {
            f32x4 v = *(const f32x4*)(src + q * 4);
            *(f16x4*)(dst + q * 4) = cvt4(v);
        }
    }
    // ---- stage interleaved W1|b1 (scalar f16 stores; thread tid owns (f,k)) ----
    {
        const int f = tid >> 4, k = tid & 15;
        const int base = f * 32 + (k >> 2) * 8 + (k & 3);   // [f][g][lo4|hi4]
        wbs[base]     = (_Float16)W1[(size_t)(f0 + f) * 16 + k];
        wbs[base + 4] = (_Float16)b1[(size_t)(f0 + f) * 16 + k];
    }
    // ---- stage (b2, w3) float2 pairs ----
    {
        const int f = tid >> 4, n = tid & 15;
        bws[tid] = make_float2(b2[(size_t)(f0 + f) * 16 + n],
                               W3[(size_t)(f0 + f) * 16 + n]);
    }
    __syncthreads();

    const _Float16* xw = xs + (w * 64 + r) * XR;

    f32x4 acc[4];     // [tile][j]: D row g4+j (batch row within tile), col r (channel)
    #pragma unroll
    for (int t = 0; t < 4; ++t) acc[t] = (f32x4){0.f, 0.f, 0.f, 0.f};

    for (int fi = 0; fi < FCHUNK; fi += 4) {   // rolled: keeps register pressure down
        f16x4 xv[4];
        #pragma unroll
        for (int t = 0; t < 4; ++t)
            xv[t] = *(const f16x4*)(xw + t * 16 * XR + fi);

        #pragma unroll
        for (int u = 0; u < 4; ++u) {
            const int f = fi + u;
            // adjacent f16x4 reads (8 B apart) -> ds_read2_b64
            f16x4 w1h   = *(const f16x4*)(wbs + f * 32 + g * 8);
            f16x4 b1h   = *(const f16x4*)(wbs + f * 32 + g * 8 + 4);
            f16x4 bfrag = *(const f16x4*)(w2s + (f * 16 + r) * 16 + g4);
            const float2 bw = bws[f * 16 + r];          // one ds_read_b64
            const float b2k = bw.x;
            const float w3k = bw.y;
            const f32x4 cinit = {b2k, b2k, b2k, b2k};   // b2 folded into MFMA C
            const f32x4 w3k4  = {w3k, w3k, w3k, w3k};

            #pragma unroll
            for (int t = 0; t < 4; ++t) {
                const _Float16 s = xv[t][u];
                f16x4 xb = {s, s, s, s};
                f16x4 h = relu_h(xb * w1h + b1h);       // v_pk_fma_f16 + v_pk_max_f16
                f32x4 d = __builtin_amdgcn_mfma_f32_16x16x16f16(h, bfrag, cinit, 0, 0, 0);
                acc[t] += relu_f(d) * w3k4;
            }
        }
    }

    // ---- channel reduce (lane bits 0..3); r==0 lanes atomic the subnet sums ----
    #pragma unroll
    for (int t = 0; t < 4; ++t)
        #pragma unroll
        for (int j = 0; j < 4; ++j) {
            float v = acc[t][j];
            v += __shfl_xor(v, 1, 64);
            v += __shfl_xor(v, 2, 64);
            v += __shfl_xor(v, 4, 64);
            v += __shfl_xor(v, 8, 64);
            if (r == 0)
                atomicAdd(out + rowbase + w * 64 + t * 16 + g4 + j, v);
        }

    // ---- linear term + constants: thread tid owns local row tid (xs intact) ----
    float b3s = 0.f;
    #pragma unroll
    for (int c = 0; c < FCHUNK; ++c) b3s += b3[f0 + c];   // uniform -> s_loads
    float lin = 0.f;
    const _Float16* xrow = xs + tid * XR;
    #pragma unroll
    for (int c = 0; c < FCHUNK; ++c)
        lin = fmaf((float)xrow[c], la[f0 + c], lin);       // la uniform -> s_loads
    atomicAdd(out + rowbase + tid, lin + b3s + (fg == 0 ? bb[0] : 0.f));
}

extern "C" void kernel_launch(void* const* d_in, const int* in_sizes, int n_in,
                              void* d_out, int out_size, void* d_ws, size_t ws_size,
                              hipStream_t stream) {
    const float* x  = (const float*)d_in[0];
    const float* la = (const float*)d_in[1];
    const float* bb = (const float*)d_in[2];
    const float* W1 = (const float*)d_in[3];
    const float* b1 = (const float*)d_in[4];
    const float* W2 = (const float*)d_in[5];
    const float* b2 = (const float*)d_in[6];
    const float* W3 = (const float*)d_in[7];
    const float* b3 = (const float*)d_in[8];
    float* out = (float*)d_out;

    (void)hipMemsetAsync(out, 0, (size_t)out_size * sizeof(float), stream);

    dim3 grid(2048), block(256);   // 128 row-blocks x 16 feature-groups
    hipLaunchKernelGGL(igann_kernel, grid, block, 0, stream,
                       x, la, bb, W1, b1, W2, b2, W3, b3, out);
}